// Round 11
// baseline (607.550 us; speedup 1.0000x reference)
//
#include <hip/hip_runtime.h>
#include <hip/hip_bf16.h>

#define LQ 16
#define DD 256
#define LP 4096
#define NBH 256

typedef __attribute__((ext_vector_type(8))) short bf16x8;
typedef __attribute__((ext_vector_type(4))) float f32x4;

static constexpr float QSC = 0.0625f * 1.44269504088896340736f; // D^-0.5 * log2(e)
static constexpr float NEGBIG = -1e30f;
static constexpr float MINIT  = -1e4f;   // exp2(MINIT)==0 in fp32; keeps m-mn finite

__device__ inline unsigned cvt2(float a, float b) {
  unsigned r;
  asm("v_cvt_pk_bf16_f32 %0, %1, %2" : "=v"(r) : "v"(a), "v"(b));
  return r;
}

union FragU { unsigned u[4]; bf16x8 v; };

__device__ inline bf16x8 pack8(float a0,float a1,float a2,float a3,
                               float a4,float a5,float a6,float a7){
  FragU x;
  x.u[0]=cvt2(a0,a1); x.u[1]=cvt2(a2,a3); x.u[2]=cvt2(a4,a5); x.u[3]=cvt2(a6,a7);
  return x.v;
}

// Lane layout: q = lane&15 (=l15), g = lane>>4.
// Swapped QK (mfma(K,Q)) on rows r0 = base + 16*dh + l15 gives this wave
// sc_own[j] = score(base + 16*dh + 4g + j, q=l15).
// s8[0..3] must map to rows base+4g+j, s8[4..7] to base+16+4g+j (pf slot
// j <-> kv = 4g + (j&3) + 16*(j>>2); V gathered to match, as R1-proven).
// R11: each wave computes only ITS 16 rows; partner's 16B f32x4 comes via an
// 8KB double-buffered LDS exchange (one __syncthreads per chunk).

__global__ __launch_bounds__(256, 4)
void attn_main(const float* __restrict__ Q, const float* __restrict__ Kp,
               const float* __restrict__ Vp, const float* __restrict__ Ka,
               const float* __restrict__ Va, const void* __restrict__ mask,
               float* __restrict__ out, float* __restrict__ dn)
{
  __shared__ __align__(16) float xch[2][2][2][64][4]; // [parity][pair][dh][lane][j] = 8 KiB

  const int tid = threadIdx.x;
  const int lane = tid & 63;
  const int wid = tid >> 6;
  const int pair = wid >> 1, dh = wid & 1;
  const int bh = blockIdx.x >> 2;
  const int pg = (blockIdx.x & 3) * 2 + pair;   // pair-global: 0..7 (512 rows each)
  const int l15 = lane & 15, g = lane >> 4;

  // mask dtype probe: bytes 4i+1 are all-zero iff mask is int32-encoded
  const unsigned char* m8all = (const unsigned char*)mask;
  unsigned probe = 0;
  for (int i = lane; i < 256; i += 64) probe |= m8all[4*i+1];
  const bool mbool = (__any(probe != 0) != 0);

  // Q fragments (B-operand), scale folded in
  const float* qb = Q + ((size_t)bh*LQ + l15)*DD + 8*g;
  bf16x8 qf[8];
  #pragma unroll
  for (int s = 0; s < 8; ++s) {
    float4 a = *(const float4*)(qb + 32*s);
    float4 b = *(const float4*)(qb + 32*s + 4);
    qf[s] = pack8(a.x*QSC,a.y*QSC,a.z*QSC,a.w*QSC,
                  b.x*QSC,b.y*QSC,b.z*QSC,b.w*QSC);
  }

  f32x4 acc[8];
  #pragma unroll
  for (int t = 0; t < 8; ++t) acc[t] = (f32x4){0.f,0.f,0.f,0.f};
  float m = MINIT, l = 0.f;

  const float* kb_bh = Kp + (size_t)bh*LP*DD;
  const float* vb_bh = Vp + (size_t)bh*LP*DD;
  const unsigned char* m8_bh = m8all + (size_t)bh*LQ*LP;
  const int* m32_bh = (const int*)mask + (size_t)bh*LQ*LP;

  const int kbase = pg * 512;

  for (int c = 0; c < 16; ++c) {
    const int k0 = kbase + 32*c;

    // ---- mask words first: consumed after barrier, hidden under K ----
    unsigned mw0 = 0xFFFFFFFFu, mw1 = 0xFFFFFFFFu;
    int4 mi0, mi1;
    {
      const int ka0 = k0 + 4*g, ka1 = k0 + 16 + 4*g;
      if (mbool) {
        mw0 = *(const unsigned*)(m8_bh + (size_t)l15*LP + ka0);
        mw1 = *(const unsigned*)(m8_bh + (size_t)l15*LP + ka1);
      } else {
        mi0 = *(const int4*)(m32_bh + (size_t)l15*LP + ka0);
        mi1 = *(const int4*)(m32_bh + (size_t)l15*LP + ka1);
      }
    }

    // ---- own 16 K rows only (dedup: partner covers the other 16) ----
    f32x4 sco = {0.f,0.f,0.f,0.f};
    {
      const float* kr = kb_bh + (size_t)(k0 + 16*dh + l15) * DD + 8*g;
      #pragma unroll
      for (int s = 0; s < 8; ++s) {
        float4 a = *(const float4*)(kr + 32*s);
        float4 b = *(const float4*)(kr + 32*s + 4);
        bf16x8 kf = pack8(a.x,a.y,a.z,a.w,b.x,b.y,b.z,b.w);
        sco = __builtin_amdgcn_mfma_f32_16x16x32_bf16(kf, qf[s], sco, 0,0,0);
      }
    }

    // ---- exchange scores with partner wave (16B each way) ----
    const int par = c & 1;
    *(f32x4*)&xch[par][pair][dh][lane][0] = sco;
    __syncthreads();                       // drains vm+lgkm; V issued after

    // ---- V loads + bf16 staging (R10-proven), issued right after barrier ----
    int vo[8];
    #pragma unroll
    for (int j = 0; j < 8; ++j) {
      const int kv = 4*g + (j&3) + 16*(j>>2);
      vo[j] = (k0 + kv) * DD + dh*128 + l15;
    }
    bf16x8 vfr[8];
    #pragma unroll
    for (int t = 0; t < 8; ++t) {
      float v0 = vb_bh[vo[0]+16*t], v1 = vb_bh[vo[1]+16*t],
            v2 = vb_bh[vo[2]+16*t], v3 = vb_bh[vo[3]+16*t];
      float v4 = vb_bh[vo[4]+16*t], v5 = vb_bh[vo[5]+16*t],
            v6 = vb_bh[vo[6]+16*t], v7 = vb_bh[vo[7]+16*t];
      vfr[t] = pack8(v0,v1,v2,v3,v4,v5,v6,v7);
    }

    // ---- reassemble s8: lo = rows k0+4g+j, hi = rows k0+16+4g+j ----
    f32x4 oth = *(const f32x4*)&xch[par][pair][dh^1][lane][0];
    const f32x4 lo = dh ? oth : sco;
    const f32x4 hi = dh ? sco : oth;

    float s8[8];
    if (mbool) {
      #pragma unroll
      for (int j = 0; j < 4; ++j) {
        s8[j]   = ((mw0>>(8*j))&0xFFu) ? lo[j] : NEGBIG;
        s8[4+j] = ((mw1>>(8*j))&0xFFu) ? hi[j] : NEGBIG;
      }
    } else {
      s8[0]=mi0.x?lo[0]:NEGBIG; s8[1]=mi0.y?lo[1]:NEGBIG;
      s8[2]=mi0.z?lo[2]:NEGBIG; s8[3]=mi0.w?lo[3]:NEGBIG;
      s8[4]=mi1.x?hi[0]:NEGBIG; s8[5]=mi1.y?hi[1]:NEGBIG;
      s8[6]=mi1.z?hi[2]:NEGBIG; s8[7]=mi1.w?hi[3]:NEGBIG;
    }

    // ---- online softmax in exp2 domain ----
    float mx = fmaxf(fmaxf(fmaxf(s8[0],s8[1]),fmaxf(s8[2],s8[3])),
                     fmaxf(fmaxf(s8[4],s8[5]),fmaxf(s8[6],s8[7])));
    mx = fmaxf(mx, __shfl_xor(mx,16));
    mx = fmaxf(mx, __shfl_xor(mx,32));
    const float mn = fmaxf(m, mx);
    const float f = __builtin_amdgcn_exp2f(m - mn);
    float p[8], ps = 0.f;
    #pragma unroll
    for (int j = 0; j < 8; ++j){ p[j] = __builtin_amdgcn_exp2f(s8[j]-mn); ps += p[j]; }
    ps += __shfl_xor(ps,16);
    ps += __shfl_xor(ps,32);
    l = l * f + ps;
    m = mn;
    #pragma unroll
    for (int t = 0; t < 8; ++t){ acc[t][0]*=f; acc[t][1]*=f; acc[t][2]*=f; acc[t][3]*=f; }

    bf16x8 pf = pack8(p[0],p[1],p[2],p[3],p[4],p[5],p[6],p[7]);

    #pragma unroll
    for (int t = 0; t < 8; ++t)
      acc[t] = __builtin_amdgcn_mfma_f32_16x16x32_bf16(vfr[t], pf, acc[t], 0,0,0);
  }

  // ---- active K/V (pg==0 waves only): R10's exchange-free 16-row path ----
  if (pg == 0) {
    const float* ka_bh = Ka + (size_t)bh*LQ*DD;
    const float* va_bh = Va + (size_t)bh*LQ*DD;
    f32x4 sc0 = {0.f,0.f,0.f,0.f};
    const float* kr0 = ka_bh + (size_t)l15*DD + 8*g;
    #pragma unroll
    for (int s = 0; s < 8; ++s) {
      float4 a = *(const float4*)(kr0 + 32*s);
      float4 b = *(const float4*)(kr0 + 32*s + 4);
      bf16x8 kf = pack8(a.x,a.y,a.z,a.w,b.x,b.y,b.z,b.w);
      sc0 = __builtin_amdgcn_mfma_f32_16x16x32_bf16(kf, qf[s], sc0, 0,0,0);
    }
    float s8[8];
    #pragma unroll
    for (int j = 0; j < 4; ++j) { s8[j] = sc0[j]; s8[4+j] = NEGBIG; }

    float mx = fmaxf(fmaxf(s8[0],s8[1]),fmaxf(s8[2],s8[3]));
    mx = fmaxf(mx, __shfl_xor(mx,16));
    mx = fmaxf(mx, __shfl_xor(mx,32));
    const float mn = fmaxf(m, mx);
    const float f = __builtin_amdgcn_exp2f(m - mn);
    float p[8], ps = 0.f;
    #pragma unroll
    for (int j = 0; j < 8; ++j){ p[j] = __builtin_amdgcn_exp2f(s8[j]-mn); ps += p[j]; }
    ps += __shfl_xor(ps,16);
    ps += __shfl_xor(ps,32);
    l = l * f + ps;
    m = mn;
    #pragma unroll
    for (int t = 0; t < 8; ++t){ acc[t][0]*=f; acc[t][1]*=f; acc[t][2]*=f; acc[t][3]*=f; }

    bf16x8 pf = pack8(p[0],p[1],p[2],p[3],p[4],p[5],p[6],p[7]);
    #pragma unroll
    for (int t = 0; t < 8; ++t) {
      const int col = dh*128 + 16*t + l15;
      float v0 = va_bh[(4*g+0)*DD + col], v1 = va_bh[(4*g+1)*DD + col],
            v2 = va_bh[(4*g+2)*DD + col], v3 = va_bh[(4*g+3)*DD + col];
      bf16x8 vf = pack8(v0,v1,v2,v3,0.f,0.f,0.f,0.f);
      acc[t] = __builtin_amdgcn_mfma_f32_16x16x32_bf16(vf, pf, acc[t], 0,0,0);
    }
  }

  // merge via fixed reference point R=0: logits*log2e is O(10), exp2 safe
  const float w = __builtin_amdgcn_exp2f(m);
  float* ob = out + ((size_t)bh*LQ + l15)*DD + dh*128 + 4*g;
  #pragma unroll
  for (int t = 0; t < 8; ++t) {
    atomicAdd(ob + 16*t + 0, w*acc[t][0]);
    atomicAdd(ob + 16*t + 1, w*acc[t][1]);
    atomicAdd(ob + 16*t + 2, w*acc[t][2]);
    atomicAdd(ob + 16*t + 3, w*acc[t][3]);
  }
  if (dh == 0 && g == 0)
    atomicAdd(dn + bh*LQ + l15, w*l);
}

__global__ void attn_norm(float* __restrict__ out, const float* __restrict__ dn)
{
  const int e = blockIdx.x * 256 + threadIdx.x;
  out[e] = out[e] / dn[e >> 8];
}

extern "C" void kernel_launch(void* const* d_in, const int* in_sizes, int n_in,
                              void* d_out, int out_size, void* d_ws, size_t ws_size,
                              hipStream_t stream) {
  const float* Q  = (const float*)d_in[0];
  const float* Kp = (const float*)d_in[1];
  const float* Vp = (const float*)d_in[2];
  const float* Ka = (const float*)d_in[3];
  const float* Va = (const float*)d_in[4];
  const void* mask = d_in[5];
  float* out = (float*)d_out;
  float* dn  = (float*)d_ws;   // 256*16 floats = 16 KB

  hipMemsetAsync(out, 0, (size_t)out_size * sizeof(float), stream);
  hipMemsetAsync(dn, 0, NBH * LQ * sizeof(float), stream);
  attn_main<<<NBH*4, 256, 0, stream>>>(Q, Kp, Vp, Ka, Va, mask, out, dn);
  attn_norm<<<(NBH*LQ*DD)/256, 256, 0, stream>>>(out, dn);
}